// Round 5
// baseline (449.837 us; speedup 1.0000x reference)
//
#include <hip/hip_runtime.h>
#include <hip/hip_bf16.h>

// AVWGCN: B=64, N=8192, Din=Dout=64, D=10, C=4, NPC=2048
// k1 (sum_EH): nodes_per is a partition of 0..N-1 (arange), so
//   sum_EH[b,d,i] = sum over ALL nodes n of relu(E[n,d])*mask[b,n]*x[b,n,i].
//   => zero-indirection streaming kernel: LDS-staged tEm per 512-node chunk,
//   lane-linear f32x4 x stream (1KB/wave-instr, no dependent loads), unroll 4.
// k2 (k_main): one wave = one node (4 waves/block); W+bias in LDS (2 barriers);
//   barrier-free main loop, z built in registers in MFMA A-frag layout
//   (verified r1-r4), depth-2 x-chunk prefetch; mfma_f32_16x16x32_bf16.

#define BB 64
#define NN 8192
#define DD 10

typedef __bf16 bf16;
typedef __bf16 bf16x8 __attribute__((ext_vector_type(8)));
typedef float f32x4 __attribute__((ext_vector_type(4)));

// ---------------- Kernel 1: sum_EH ----------------
// grid = 64 b * 16 chunks (512 nodes each), block = 256 (4 waves)
__global__ __launch_bounds__(256, 4) void k_sumEH(
    const float* __restrict__ x, const float* __restrict__ emb,
    const float* __restrict__ mask, float* __restrict__ sEH) {
  __shared__ float m_l[512];
  __shared__ float tEm[512][DD];                  // 20 KB
  __shared__ __align__(16) float red[4][DD][64];  // 10 KB

  const int b = blockIdx.x >> 4;
  const int chunk = blockIdx.x & 15;
  const int tid = threadIdx.x;
  const int lane = tid & 63;
  const int w = tid >> 6;
  const int node0 = chunk * 512;

  // stage mask row chunk (coalesced, contiguous)
  for (int s = tid; s < 512; s += 256) m_l[s] = mask[(size_t)b * NN + node0 + s];
  __syncthreads();
  // stage tEm = relu(emb)*mask (emb chunk is 5120 contiguous floats)
  for (int s = tid; s < 512 * DD; s += 256) {
    const int nl = s / DD, d = s - nl * DD;
    tEm[nl][d] = fmaxf(emb[(size_t)node0 * DD + s], 0.f) * m_l[nl];
  }
  __syncthreads();

  // main stream: wave w owns nodes [w*128, w*128+128); per instr 4 nodes x 1KB contiguous
  const int nsub = lane >> 4, r16 = lane & 15;
  const f32x4* xb4 = (const f32x4*)(x + ((size_t)b * NN + node0 + w * 128) * 64);

  f32x4 acc[DD];
#pragma unroll
  for (int d = 0; d < DD; ++d) acc[d] = (f32x4)0.f;

#pragma unroll 4
  for (int g = 0; g < 32; ++g) {
    const f32x4 xv = xb4[g * 64 + lane];  // address linear in g: no dependencies
    const int nl = w * 128 + g * 4 + nsub;
    const float2 t01 = *(const float2*)&tEm[nl][0];
    const float2 t23 = *(const float2*)&tEm[nl][2];
    const float2 t45 = *(const float2*)&tEm[nl][4];
    const float2 t67 = *(const float2*)&tEm[nl][6];
    const float2 t89 = *(const float2*)&tEm[nl][8];
    acc[0] += xv * t01.x; acc[1] += xv * t01.y;
    acc[2] += xv * t23.x; acc[3] += xv * t23.y;
    acc[4] += xv * t45.x; acc[5] += xv * t45.y;
    acc[6] += xv * t67.x; acc[7] += xv * t67.y;
    acc[8] += xv * t89.x; acc[9] += xv * t89.y;
  }

  // reduce across the 4 node-subgroups (lanes l, l^16, l^32, l^48)
#pragma unroll
  for (int d = 0; d < DD; ++d) {
    f32x4 a = acc[d];
#pragma unroll
    for (int j = 0; j < 4; ++j) {
      float v = a[j];
      v += __shfl_xor(v, 16);
      v += __shfl_xor(v, 32);
      a[j] = v;
    }
    acc[d] = a;
  }
  if (nsub == 0) {
#pragma unroll
    for (int d = 0; d < DD; ++d) *(f32x4*)&red[w][d][r16 * 4] = acc[d];
  }
  __syncthreads();

  for (int s = tid; s < DD * 64; s += 256) {
    const int d = s >> 6, i = s & 63;
    const float v = red[0][d][i] + red[1][d][i] + red[2][d][i] + red[3][d][i];
    atomicAdd(sEH + ((size_t)b * DD + d) * 64 + i, v);
  }
}

// ---------------- Kernel 2: main ----------------
// grid = N/4 = 2048 blocks, block = 256 (4 waves). One wave = one node.
__global__ __launch_bounds__(256, 4) void k_main(
    const float* __restrict__ x, const float* __restrict__ emb,
    const float* __restrict__ mask, const float* __restrict__ wp,
    const float* __restrict__ bp, const int* __restrict__ np,
    const float* __restrict__ sEH, float* __restrict__ out) {
  __shared__ float E_l[4][DD];
  __shared__ float bb_l[4][64];
  __shared__ float mask_l[64][4];
  __shared__ __align__(16) bf16 Wt[4][64][72];  // [g][o][i], pad 72

  const int tid = threadIdx.x;
  const int lane = tid & 63;
  const int w = tid >> 6;          // wave = node index within block
  const int p0 = blockIdx.x * 4;   // base output position
  const int c = p0 >> 11;          // client

  // stage mask[64 b][4 g] and E[4 g][10 d]
  {
    const int bq = tid >> 2, g = tid & 3;
    mask_l[bq][g] = mask[(size_t)bq * NN + np[p0 + g]];
  }
  if (tid < 40) {
    const int g = tid / 10, d = tid % 10;
    E_l[g][d] = emb[(size_t)np[p0 + g] * DD + d];
  }
  __syncthreads();

  // W-build: wave w owns i in [w*16, w*16+16); lane = o. All 4 nodes at once (pk-fma).
  {
    f32x4 accW[16];
#pragma unroll
    for (int p = 0; p < 16; ++p) accW[p] = (f32x4)0.f;
#pragma unroll
    for (int d = 0; d < DD; ++d) {
      f32x4 ev;
      ev[0] = E_l[0][d]; ev[1] = E_l[1][d]; ev[2] = E_l[2][d]; ev[3] = E_l[3][d];
      const float* base = wp + ((size_t)(c * DD + d) * 64 + w * 16) * 64 + lane;
#pragma unroll
      for (int p = 0; p < 16; ++p) accW[p] += ev * base[(size_t)p * 64];
    }
#pragma unroll
    for (int g = 0; g < 4; ++g) {
      bf16x8 v0, v1;
#pragma unroll
      for (int p = 0; p < 8; ++p) { v0[p] = (bf16)accW[p][g]; v1[p] = (bf16)accW[p + 8][g]; }
      *(bf16x8*)&Wt[g][lane][w * 16] = v0;
      *(bf16x8*)&Wt[g][lane][w * 16 + 8] = v1;
    }
    // bias for node w (lane = o)
    float bacc = 0.f;
#pragma unroll
    for (int d = 0; d < DD; ++d)
      bacc = fmaf(E_l[w][d], bp[((size_t)(c * DD + d)) * 64 + lane], bacc);
    bb_l[w][lane] = bacc;
  }
  __syncthreads();

  const int mynode = np[p0 + w];
  const int q = lane >> 4, r16 = lane & 15;
  const f32x4* x4 = (const f32x4*)x;
  const f32x4* s4 = (const f32x4*)sEH;

  // issue chunk-0 x loads FIRST (long latency), then hoist LDS state under them
  f32x4 xpre[2][4];
  auto load_x = [&](int chunk, f32x4* dst) {
    const int b = chunk * 16 + r16;
    const size_t xrow = ((size_t)b * NN + mynode) * 16;  // f32x4 units
    dst[0] = x4[xrow + q * 2 + 0];
    dst[1] = x4[xrow + q * 2 + 1];
    dst[2] = x4[xrow + 8 + q * 2 + 0];
    dst[3] = x4[xrow + 8 + q * 2 + 1];
  };
  load_x(0, xpre[0]);

  bf16x8 wfrag[4][2];
#pragma unroll
  for (int nt = 0; nt < 4; ++nt)
#pragma unroll
    for (int kt = 0; kt < 2; ++kt)
      wfrag[nt][kt] = *(const bf16x8*)&Wt[w][nt * 16 + r16][kt * 32 + q * 8];

  float biasv[4];
#pragma unroll
  for (int nt = 0; nt < 4; ++nt) biasv[nt] = bb_l[w][nt * 16 + r16];

  float tEr[DD];
#pragma unroll
  for (int d = 0; d < DD; ++d) tEr[d] = fmaxf(E_l[w][d], 0.f);

#pragma unroll
  for (int chunk = 0; chunk < 4; ++chunk) {
    if (chunk < 3) load_x(chunk + 1, xpre[(chunk + 1) & 1]);  // prefetch next chunk
    const f32x4* xa = xpre[chunk & 1];
    const int b = chunk * 16 + r16;
    const float m = mask_l[b][w];
    // z for (b=r16, i = kt*32 + q*8 + 0..7) -- exactly the MFMA A-frag layout
    f32x4 z00 = xa[0] * m;
    f32x4 z01 = xa[1] * m;
    f32x4 z10 = xa[2] * m;
    f32x4 z11 = xa[3] * m;
    const f32x4* sb = s4 + (size_t)b * DD * 16 + q * 2;
#pragma unroll
    for (int d = 0; d < DD; ++d) {
      const f32x4 s0 = sb[d * 16 + 0];
      const f32x4 s1 = sb[d * 16 + 1];
      const f32x4 s2 = sb[d * 16 + 8];
      const f32x4 s3 = sb[d * 16 + 9];
      const float t = tEr[d];
      z00 += s0 * t;
      z01 += s1 * t;
      z10 += s2 * t;
      z11 += s3 * t;
    }
    bf16x8 a0, a1;
#pragma unroll
    for (int j = 0; j < 4; ++j) {
      a0[j] = (bf16)z00[j];
      a0[4 + j] = (bf16)z01[j];
      a1[j] = (bf16)z10[j];
      a1[4 + j] = (bf16)z11[j];
    }
    f32x4 acc[4];
#pragma unroll
    for (int nt = 0; nt < 4; ++nt) {
      acc[nt][0] = biasv[nt]; acc[nt][1] = biasv[nt];
      acc[nt][2] = biasv[nt]; acc[nt][3] = biasv[nt];
    }
#pragma unroll
    for (int nt = 0; nt < 4; ++nt) {
      acc[nt] = __builtin_amdgcn_mfma_f32_16x16x32_bf16(a0, wfrag[nt][0], acc[nt], 0, 0, 0);
      acc[nt] = __builtin_amdgcn_mfma_f32_16x16x32_bf16(a1, wfrag[nt][1], acc[nt], 0, 0, 0);
    }
    // store: D row = q*4+r (b_loc), col = r16 (o within n-tile)
    const size_t pg = (size_t)(p0 + w);
#pragma unroll
    for (int nt = 0; nt < 4; ++nt) {
#pragma unroll
      for (int r = 0; r < 4; ++r) {
        const int bg = chunk * 16 + q * 4 + r;
        out[((size_t)bg * NN + pg) * 64 + nt * 16 + r16] = acc[nt][r];
      }
    }
  }
}

extern "C" void kernel_launch(void* const* d_in, const int* in_sizes, int n_in,
                              void* d_out, int out_size, void* d_ws, size_t ws_size,
                              hipStream_t stream) {
  const float* x    = (const float*)d_in[0];
  const float* emb  = (const float*)d_in[1];
  // d_in[2] = poly_coefficients (unused in sprtrelu mode)
  const float* mask = (const float*)d_in[3];
  const float* wp   = (const float*)d_in[4];
  const float* bp   = (const float*)d_in[5];
  const int*   np   = (const int*)d_in[6];
  float* out = (float*)d_out;
  float* sEH = (float*)d_ws;  // [64][10][64] f32 = 160 KB

  hipMemsetAsync(sEH, 0, (size_t)BB * DD * 64 * sizeof(float), stream);
  k_sumEH<<<dim3(BB * 16), dim3(256), 0, stream>>>(x, emb, mask, sEH);
  k_main<<<dim3(NN / 4), dim3(256), 0, stream>>>(x, emb, mask, wp, bp, np, sEH, out);
}

// Round 6
// 415.261 us; speedup vs baseline: 1.0833x; 1.0833x over previous
//
#include <hip/hip_runtime.h>
#include <hip/hip_bf16.h>

// AVWGCN: B=64, N=8192, Din=Dout=64, D=10, C=4, NPC=2048
// k1 (sum_EH): nodes_per is arange (partition) -> no indirection.
//   Per (b, 512-node chunk): stage relu(E)*mask in LDS, then stream x with a
//   FORCED 8-deep batch of f32x4 loads (8KB/wave in flight) -> latency A/B test.
// k2 (k_main): r4 spill-free structure (one wave = one node, barrier-free main
//   loop, z in registers in MFMA A-frag layout) + depth-2 x prefetch, (256,2).

#define BB 64
#define NN 8192
#define DD 10

typedef __bf16 bf16;
typedef __bf16 bf16x8 __attribute__((ext_vector_type(8)));
typedef float f32x4 __attribute__((ext_vector_type(4)));

// ---------------- Kernel 1: sum_EH ----------------
// grid = 64 b * 16 chunks (512 nodes each), block = 256 (4 waves)
__global__ __launch_bounds__(256, 2) void k_sumEH(
    const float* __restrict__ x, const float* __restrict__ emb,
    const float* __restrict__ mask, float* __restrict__ sEH) {
  __shared__ float m_l[512];
  __shared__ float tEm[512][DD];                  // 20 KB
  __shared__ __align__(16) float red[4][DD][64];  // 10 KB

  const int b = blockIdx.x >> 4;
  const int chunk = blockIdx.x & 15;
  const int tid = threadIdx.x;
  const int lane = tid & 63;
  const int w = tid >> 6;
  const int node0 = chunk * 512;

  for (int s = tid; s < 512; s += 256) m_l[s] = mask[(size_t)b * NN + node0 + s];
  __syncthreads();
  for (int s = tid; s < 512 * DD; s += 256) {
    const int nl = s / DD, d = s - nl * DD;
    tEm[nl][d] = fmaxf(emb[(size_t)node0 * DD + s], 0.f) * m_l[nl];
  }
  __syncthreads();

  const int nsub = lane >> 4, r16 = lane & 15;
  const f32x4* xb4 = (const f32x4*)(x + ((size_t)b * NN + node0 + w * 128) * 64);

  f32x4 acc[DD];
#pragma unroll
  for (int d = 0; d < DD; ++d) acc[d] = (f32x4)0.f;

  // 4 super-iterations; each: 8 independent 1KB loads issued back-to-back
  // (8 KB/wave outstanding), THEN 80 pk-FMAs consuming them.
#pragma unroll
  for (int gg = 0; gg < 4; ++gg) {
    f32x4 xv[8];
#pragma unroll
    for (int t = 0; t < 8; ++t) xv[t] = xb4[(gg * 8 + t) * 64 + lane];
#pragma unroll
    for (int t = 0; t < 8; ++t) {
      const int nl = w * 128 + (gg * 8 + t) * 4 + nsub;
      const float2 t01 = *(const float2*)&tEm[nl][0];
      const float2 t23 = *(const float2*)&tEm[nl][2];
      const float2 t45 = *(const float2*)&tEm[nl][4];
      const float2 t67 = *(const float2*)&tEm[nl][6];
      const float2 t89 = *(const float2*)&tEm[nl][8];
      const f32x4 xvt = xv[t];
      acc[0] += xvt * t01.x; acc[1] += xvt * t01.y;
      acc[2] += xvt * t23.x; acc[3] += xvt * t23.y;
      acc[4] += xvt * t45.x; acc[5] += xvt * t45.y;
      acc[6] += xvt * t67.x; acc[7] += xvt * t67.y;
      acc[8] += xvt * t89.x; acc[9] += xvt * t89.y;
    }
  }

  // reduce across the 4 node-subgroups (lanes l, l^16, l^32, l^48)
#pragma unroll
  for (int d = 0; d < DD; ++d) {
    f32x4 a = acc[d];
#pragma unroll
    for (int j = 0; j < 4; ++j) {
      float v = a[j];
      v += __shfl_xor(v, 16);
      v += __shfl_xor(v, 32);
      a[j] = v;
    }
    acc[d] = a;
  }
  if (nsub == 0) {
#pragma unroll
    for (int d = 0; d < DD; ++d) *(f32x4*)&red[w][d][r16 * 4] = acc[d];
  }
  __syncthreads();

  for (int s = tid; s < DD * 64; s += 256) {
    const int d = s >> 6, i = s & 63;
    const float v = red[0][d][i] + red[1][d][i] + red[2][d][i] + red[3][d][i];
    atomicAdd(sEH + ((size_t)b * DD + d) * 64 + i, v);
  }
}

// ---------------- Kernel 2: main ----------------
// grid = N/4 = 2048 blocks, block = 256 (4 waves). One wave = one node.
__global__ __launch_bounds__(256, 2) void k_main(
    const float* __restrict__ x, const float* __restrict__ emb,
    const float* __restrict__ mask, const float* __restrict__ wp,
    const float* __restrict__ bp, const int* __restrict__ np,
    const float* __restrict__ sEH, float* __restrict__ out) {
  __shared__ float E_l[4][DD];
  __shared__ float bb_l[4][64];
  __shared__ float mask_l[64][4];
  __shared__ __align__(16) bf16 Wt[4][64][72];  // [g][o][i], pad 72

  const int tid = threadIdx.x;
  const int lane = tid & 63;
  const int w = tid >> 6;          // wave = node index within block
  const int p0 = blockIdx.x * 4;   // base output position
  const int c = p0 >> 11;          // client

  {
    const int bq = tid >> 2, g = tid & 3;
    mask_l[bq][g] = mask[(size_t)bq * NN + np[p0 + g]];
  }
  if (tid < 40) {
    const int g = tid / 10, d = tid % 10;
    E_l[g][d] = emb[(size_t)np[p0 + g] * DD + d];
  }
  __syncthreads();

  // W-build: wave w owns i in [w*16, w*16+16); lane = o. All 4 nodes at once (pk-fma).
  {
    f32x4 accW[16];
#pragma unroll
    for (int p = 0; p < 16; ++p) accW[p] = (f32x4)0.f;
#pragma unroll
    for (int d = 0; d < DD; ++d) {
      f32x4 ev;
      ev[0] = E_l[0][d]; ev[1] = E_l[1][d]; ev[2] = E_l[2][d]; ev[3] = E_l[3][d];
      const float* base = wp + ((size_t)(c * DD + d) * 64 + w * 16) * 64 + lane;
#pragma unroll
      for (int p = 0; p < 16; ++p) accW[p] += ev * base[(size_t)p * 64];
    }
#pragma unroll
    for (int g = 0; g < 4; ++g) {
      bf16x8 v0, v1;
#pragma unroll
      for (int p = 0; p < 8; ++p) { v0[p] = (bf16)accW[p][g]; v1[p] = (bf16)accW[p + 8][g]; }
      *(bf16x8*)&Wt[g][lane][w * 16] = v0;
      *(bf16x8*)&Wt[g][lane][w * 16 + 8] = v1;
    }
    float bacc = 0.f;
#pragma unroll
    for (int d = 0; d < DD; ++d)
      bacc = fmaf(E_l[w][d], bp[((size_t)(c * DD + d)) * 64 + lane], bacc);
    bb_l[w][lane] = bacc;
  }
  __syncthreads();

  const int mynode = np[p0 + w];
  const int q = lane >> 4, r16 = lane & 15;
  const f32x4* x4 = (const f32x4*)x;
  const f32x4* s4 = (const f32x4*)sEH;

  f32x4 xpre[2][4];
  auto load_x = [&](int chunk, f32x4* dst) {
    const int b = chunk * 16 + r16;
    const size_t xrow = ((size_t)b * NN + mynode) * 16;  // f32x4 units
    dst[0] = x4[xrow + q * 2 + 0];
    dst[1] = x4[xrow + q * 2 + 1];
    dst[2] = x4[xrow + 8 + q * 2 + 0];
    dst[3] = x4[xrow + 8 + q * 2 + 1];
  };
  load_x(0, xpre[0]);

  bf16x8 wfrag[4][2];
#pragma unroll
  for (int nt = 0; nt < 4; ++nt)
#pragma unroll
    for (int kt = 0; kt < 2; ++kt)
      wfrag[nt][kt] = *(const bf16x8*)&Wt[w][nt * 16 + r16][kt * 32 + q * 8];

  float biasv[4];
#pragma unroll
  for (int nt = 0; nt < 4; ++nt) biasv[nt] = bb_l[w][nt * 16 + r16];

  float tEr[DD];
#pragma unroll
  for (int d = 0; d < DD; ++d) tEr[d] = fmaxf(E_l[w][d], 0.f);

#pragma unroll
  for (int chunk = 0; chunk < 4; ++chunk) {
    if (chunk < 3) load_x(chunk + 1, xpre[(chunk + 1) & 1]);
    const f32x4* xa = xpre[chunk & 1];
    const int b = chunk * 16 + r16;
    const float m = mask_l[b][w];
    f32x4 z00 = xa[0] * m;
    f32x4 z01 = xa[1] * m;
    f32x4 z10 = xa[2] * m;
    f32x4 z11 = xa[3] * m;
    const f32x4* sb = s4 + (size_t)b * DD * 16 + q * 2;
#pragma unroll
    for (int d = 0; d < DD; ++d) {
      const f32x4 s0 = sb[d * 16 + 0];
      const f32x4 s1 = sb[d * 16 + 1];
      const f32x4 s2 = sb[d * 16 + 8];
      const f32x4 s3 = sb[d * 16 + 9];
      const float t = tEr[d];
      z00 += s0 * t;
      z01 += s1 * t;
      z10 += s2 * t;
      z11 += s3 * t;
    }
    bf16x8 a0, a1;
#pragma unroll
    for (int j = 0; j < 4; ++j) {
      a0[j] = (bf16)z00[j];
      a0[4 + j] = (bf16)z01[j];
      a1[j] = (bf16)z10[j];
      a1[4 + j] = (bf16)z11[j];
    }
    f32x4 acc[4];
#pragma unroll
    for (int nt = 0; nt < 4; ++nt) {
      acc[nt][0] = biasv[nt]; acc[nt][1] = biasv[nt];
      acc[nt][2] = biasv[nt]; acc[nt][3] = biasv[nt];
    }
#pragma unroll
    for (int nt = 0; nt < 4; ++nt) {
      acc[nt] = __builtin_amdgcn_mfma_f32_16x16x32_bf16(a0, wfrag[nt][0], acc[nt], 0, 0, 0);
      acc[nt] = __builtin_amdgcn_mfma_f32_16x16x32_bf16(a1, wfrag[nt][1], acc[nt], 0, 0, 0);
    }
    const size_t pg = (size_t)(p0 + w);
#pragma unroll
    for (int nt = 0; nt < 4; ++nt) {
#pragma unroll
      for (int r = 0; r < 4; ++r) {
        const int bg = chunk * 16 + q * 4 + r;
        out[((size_t)bg * NN + pg) * 64 + nt * 16 + r16] = acc[nt][r];
      }
    }
  }
}

extern "C" void kernel_launch(void* const* d_in, const int* in_sizes, int n_in,
                              void* d_out, int out_size, void* d_ws, size_t ws_size,
                              hipStream_t stream) {
  const float* x    = (const float*)d_in[0];
  const float* emb  = (const float*)d_in[1];
  // d_in[2] = poly_coefficients (unused in sprtrelu mode)
  const float* mask = (const float*)d_in[3];
  const float* wp   = (const float*)d_in[4];
  const float* bp   = (const float*)d_in[5];
  const int*   np   = (const int*)d_in[6];
  float* out = (float*)d_out;
  float* sEH = (float*)d_ws;  // [64][10][64] f32 = 160 KB

  hipMemsetAsync(sEH, 0, (size_t)BB * DD * 64 * sizeof(float), stream);
  k_sumEH<<<dim3(BB * 16), dim3(256), 0, stream>>>(x, emb, mask, sEH);
  k_main<<<dim3(NN / 4), dim3(256), 0, stream>>>(x, emb, mask, wp, bp, np, sEH, out);
}